// Round 4
// baseline (296.558 us; speedup 1.0000x reference)
//
#include <hip/hip_runtime.h>
#include <hip/hip_bf16.h>
#include <math.h>

typedef __attribute__((ext_vector_type(4))) float f32x4;
typedef __attribute__((ext_vector_type(16))) float f32x16;
typedef __attribute__((ext_vector_type(8))) short s16x8;
typedef __attribute__((ext_vector_type(4))) unsigned u32x4;

#define LDSP(p) ((__attribute__((address_space(3))) void*)(p))
#define GLBP(p) ((const __attribute__((address_space(1))) void*)(p))

__device__ __forceinline__ unsigned short f2b(float f) {
  unsigned u = __builtin_bit_cast(unsigned, f);
  u += 0x7FFFu + ((u >> 16) & 1u);
  return (unsigned short)(u >> 16);
}
__device__ __forceinline__ float b2f(unsigned short h) {
  unsigned u = ((unsigned)h) << 16;
  return __builtin_bit_cast(float, u);
}
__device__ __forceinline__ unsigned cvtpk_bf16(float lo, float hi) {
  unsigned r;
  asm("v_cvt_pk_bf16_f32 %0, %1, %2" : "=v"(r) : "v"(lo), "v"(hi));
  return r;
}

// ---------------- fp32 -> bf16 convert (vectorized, 8 elems/thread) ----------------
__global__ void cvt_f2b_kernel(const float* __restrict__ src, unsigned short* __restrict__ dst, int n8) {
  int i = blockIdx.x * blockDim.x + threadIdx.x;
  if (i >= n8) return;
  const float4* s = (const float4*)src;
  float4 a = s[2 * i], b = s[2 * i + 1];
  s16x8 o;
  o[0] = (short)f2b(a.x); o[1] = (short)f2b(a.y); o[2] = (short)f2b(a.z); o[3] = (short)f2b(a.w);
  o[4] = (short)f2b(b.x); o[5] = (short)f2b(b.y); o[6] = (short)f2b(b.z); o[7] = (short)f2b(b.w);
  ((s16x8*)dst)[i] = o;
}

// ---------------- RoPE cos/sin table: [2048][32] ----------------
__global__ void rope_table_kernel(float* __restrict__ cosT, float* __restrict__ sinT) {
  int idx = blockIdx.x * 256 + threadIdx.x;  // 65536
  int s = idx >> 5, j = idx & 31;
  float freq = (float)(1.0 / pow(10000.0, (double)(2 * j) / 64.0));
  float fm = (float)s * freq;
  cosT[idx] = cosf(fm);
  sinT[idx] = sinf(fm);
}

// ---------------- RoPE in-place on [b*h][s][64] bf16, fused scale ----------------
__global__ void rope_apply_kernel(unsigned short* __restrict__ qk, const float* __restrict__ cosT,
                                  const float* __restrict__ sinT, float scale) {
  int i = blockIdx.x * 256 + threadIdx.x;  // 1048576 groups of 8 elems
  int e = i * 8;
  int s = (e >> 6) & 2047;
  int jb = (e & 63) >> 1;
  s16x8 v = ((const s16x8*)qk)[i];
  float4 c = *(const float4*)(cosT + s * 32 + jb);
  float4 sn = *(const float4*)(sinT + s * 32 + jb);
  float cc[4] = {c.x, c.y, c.z, c.w}, ss[4] = {sn.x, sn.y, sn.z, sn.w};
  s16x8 o;
#pragma unroll
  for (int p = 0; p < 4; ++p) {
    float e_ = b2f((unsigned short)v[2 * p]);
    float o_ = b2f((unsigned short)v[2 * p + 1]);
    o[2 * p]     = (short)f2b((e_ * cc[p] - o_ * ss[p]) * scale);
    o[2 * p + 1] = (short)f2b((e_ * ss[p] + o_ * cc[p]) * scale);
  }
  ((s16x8*)qk)[i] = o;
}

// ---------------- GEMM: C[m][n] = sum_k A[m][k] * B[n][k]  (B^T layout) ----------------
// 256x128 tile, BK=64, 8 waves (2M x 4N), double-buffered LDS, ONE vmcnt(0)+barrier
// per K-tile (64 MFMAs amortize each drain). Both-sides XOR swizzle, XCD block swizzle.
// EPI=0: fp32 C row-major [M][N].  EPI=1: QKV split + permute to [b,h,s,dk] bf16.
template <int EPI>
__global__ __launch_bounds__(512, 2) void gemm256_kernel(
    const unsigned short* __restrict__ A, const unsigned short* __restrict__ B,
    float* __restrict__ Cf, unsigned short* __restrict__ Cq,
    unsigned short* __restrict__ Ck, unsigned short* __restrict__ Cv,
    int M, int N, int K) {
  __shared__ __align__(16) unsigned short As[2][256 * 64];   // 64 KB
  __shared__ __align__(16) unsigned short Bs[2][128 * 64];   // 32 KB
  const int t = threadIdx.x;
  const int lane = t & 63;
  const int w = t >> 6;
  const int wm = w >> 2, wn = w & 3;
  const int g = lane >> 4, q = lane & 15;
  // XCD-chunked bijective block swizzle (gridDim.x % 8 == 0 for both call sites)
  const int nwg = gridDim.x;
  const int bid = blockIdx.x;
  const int sid = (bid & 7) * (nwg >> 3) + (bid >> 3);
  const int m0 = (sid & 31) * 256;      // 32 M-blocks (M = 8192)
  const int n0 = (sid >> 5) * 128;
  const int srow = t >> 3;              // 0..63
  const int scol = (t & 7) << 4;        // byte col 0..112
  const size_t rbA = (size_t)K * 2;     // row bytes

  f32x4 acc[8][2] = {};
  const int nkt = K >> 6;

  // stage K-tile kt into buffer b (A: 4 passes of 64 rows; B: 2 passes)
  auto stage = [&](int b, int kt) {
    const size_t kof = (size_t)kt * 128;   // byte offset into row
#pragma unroll
    for (int p = 0; p < 4; ++p) {
      int row = p * 64 + srow;
      int cg = scol ^ ((row & 7) << 4);
      const char* ga = (const char*)A + (size_t)(m0 + row) * rbA + kof + cg;
      __builtin_amdgcn_global_load_lds(GLBP(ga), LDSP((char*)As[b] + p * 8192 + t * 16), 16, 0, 0);
    }
#pragma unroll
    for (int p = 0; p < 2; ++p) {
      int row = p * 64 + srow;
      int cg = scol ^ ((row & 7) << 4);
      const char* gb = (const char*)B + (size_t)(n0 + row) * rbA + kof + cg;
      __builtin_amdgcn_global_load_lds(GLBP(gb), LDSP((char*)Bs[b] + p * 8192 + t * 16), 16, 0, 0);
    }
  };

  stage(0, 0);
  asm volatile("s_waitcnt vmcnt(0)" ::: "memory");
  __syncthreads();

  for (int kt = 0; kt < nkt; ++kt) {
    const int cur = kt & 1;
    if (kt + 1 < nkt) stage(cur ^ 1, kt + 1);   // prefetch flies under this tile's MFMAs
    const char* ab = (const char*)As[cur];
    const char* bb = (const char*)Bs[cur];
    const int sw = (q & 7) << 4;
#pragma unroll
    for (int kk = 0; kk < 2; ++kk) {
      const int cb = kk * 64 + g * 16;
      s16x8 bf[2], af[8];
#pragma unroll
      for (int ni = 0; ni < 2; ++ni)
        bf[ni] = *(const s16x8*)(bb + (wn * 32 + ni * 16 + q) * 128 + (cb ^ sw));
#pragma unroll
      for (int mi = 0; mi < 8; ++mi)
        af[mi] = *(const s16x8*)(ab + (wm * 128 + mi * 16 + q) * 128 + (cb ^ sw));
      __builtin_amdgcn_s_setprio(1);
#pragma unroll
      for (int mi = 0; mi < 8; ++mi)
#pragma unroll
        for (int ni = 0; ni < 2; ++ni)
          acc[mi][ni] = __builtin_amdgcn_mfma_f32_16x16x32_bf16(af[mi], bf[ni], acc[mi][ni], 0, 0, 0);
      __builtin_amdgcn_s_setprio(0);
    }
    asm volatile("s_waitcnt vmcnt(0)" ::: "memory");   // drain own prefetch before publishing
    __syncthreads();                                    // all waves done reading buf[cur]
  }

  if (EPI == 0) {
#pragma unroll
    for (int mi = 0; mi < 8; ++mi)
#pragma unroll
      for (int r = 0; r < 4; ++r) {
        int m = m0 + wm * 128 + mi * 16 + g * 4 + r;
#pragma unroll
        for (int ni = 0; ni < 2; ++ni) {
          int n = n0 + wn * 32 + ni * 16 + q;
          Cf[(size_t)m * N + n] = acc[mi][ni][r];
        }
      }
  } else {
    unsigned short* dst = (n0 < 1024) ? Cq : (n0 < 2048 ? Ck : Cv);
    const int obase = n0 & 1023;
#pragma unroll
    for (int mi = 0; mi < 8; ++mi)
#pragma unroll
      for (int r = 0; r < 4; ++r) {
        int m = m0 + wm * 128 + mi * 16 + g * 4 + r;
        int bb2 = m >> 11, s = m & 2047;
#pragma unroll
        for (int ni = 0; ni < 2; ++ni) {
          int o = obase + wn * 32 + ni * 16 + q;
          int hh = o >> 6, d = o & 63;
          dst[(((size_t)bb2 * 16 + hh) * 2048 + s) * 64 + d] = f2b(acc[mi][ni][r]);
        }
      }
  }
}

// ---------------- Flash attention (swapped-QK^T, 32x32 MFMA, in-register softmax) ---------
// (unchanged from round 3)
#define BUILD_PA(dst, SS, B) {                                        \
    unsigned X  = cvtpk_bf16(SS[B + 0], SS[B + 1]);                   \
    unsigned X2 = cvtpk_bf16(SS[B + 2], SS[B + 3]);                   \
    unsigned Y  = cvtpk_bf16(SS[B + 4], SS[B + 5]);                   \
    unsigned Y2 = cvtpk_bf16(SS[B + 6], SS[B + 7]);                   \
    asm volatile("v_permlane32_swap_b32 %0, %1" : "+v"(X), "+v"(Y));  \
    asm volatile("v_permlane32_swap_b32 %0, %1" : "+v"(X2), "+v"(Y2));\
    u32x4 pw_; pw_[0] = X; pw_[1] = X2; pw_[2] = Y; pw_[3] = Y2;      \
    dst = __builtin_bit_cast(s16x8, pw_); }

__global__ void attn_kernel(const unsigned short* __restrict__ Q, const unsigned short* __restrict__ K,
                            const unsigned short* __restrict__ V, unsigned short* __restrict__ O) {
  __shared__ __align__(16) unsigned short Ks[2][64 * 64];   // swizzled K tiles (double-buffered)
  __shared__ __align__(16) unsigned short Vt[2][64 * 72];   // V^T, padded stride 72
  const int t = threadIdx.x;
  const int lane = t & 63, w = t >> 6;
  const int h = lane >> 5, ql = lane & 31;
  const int bh = blockIdx.x;
  const int qt = 15 - (int)blockIdx.y;      // big q-blocks first
  const size_t hoff = (size_t)bh * 2048 * 64;
  const int q_global = qt * 128 + w * 32 + ql;
  const int qmax_w = qt * 128 + w * 32 + 31;

  s16x8 qf[4];
  {
    const unsigned short* qp = Q + hoff + (size_t)q_global * 64 + h * 8;
#pragma unroll
    for (int s = 0; s < 4; ++s) qf[s] = *(const s16x8*)(qp + 16 * s);
  }
  f32x16 accO[2] = {};
  float mrun = -3e38f, lrun = 0.f;

  const int srow = t >> 3, scol = (t & 7) << 4;
  const int kv0 = 2 * (lane & 31);
  const int dbase = w * 16 + (lane >> 5) * 8;
  const int ntk = 2 * qt + 2;
  s16x8 va = {}, vb2 = {};

  for (int it = 0; it <= ntk; ++it) {
    const int buf = it & 1;
    if (it < ntk) {
      const char* kbp = (const char*)(K + hoff) + (size_t)it * 8192;
#pragma unroll
      for (int p = 0; p < 2; ++p) {
        int row = p * 32 + srow;
        int cg = scol ^ ((row & 7) << 4);
        __builtin_amdgcn_global_load_lds(GLBP(kbp + row * 128 + cg),
                                         LDSP((char*)Ks[buf] + p * 4096 + w * 1024), 16, 0, 0);
      }
      const unsigned short* vbp = V + hoff + (size_t)it * 4096;
      va  = *(const s16x8*)(vbp + kv0 * 64 + dbase);
      vb2 = *(const s16x8*)(vbp + (kv0 + 1) * 64 + dbase);
    }
    const int tkc = it - 1;
    if (tkc >= 0 && tkc * 64 <= qmax_w) {
      const int cb2 = tkc & 1;
      f32x16 S0 = {}, S1 = {};
      __builtin_amdgcn_s_setprio(1);
#pragma unroll
      for (int s = 0; s < 4; ++s) {
        const int cb = 16 * h + 32 * s;
        const int sw = (ql & 7) << 4;
        s16x8 kf0 = *(const s16x8*)((const char*)Ks[cb2] + ql * 128 + (cb ^ sw));
        S0 = __builtin_amdgcn_mfma_f32_32x32x16_bf16(kf0, qf[s], S0, 0, 0, 0);
        s16x8 kf1 = *(const s16x8*)((const char*)Ks[cb2] + (32 + ql) * 128 + (cb ^ sw));
        S1 = __builtin_amdgcn_mfma_f32_32x32x16_bf16(kf1, qf[s], S1, 0, 0, 0);
      }
      __builtin_amdgcn_s_setprio(0);
      if (tkc * 64 + 63 > qt * 128 + w * 32) {
        const int kvb = tkc * 64 + 4 * h;
#pragma unroll
        for (int r = 0; r < 16; ++r) {
          const int kvl = (r & 3) + 8 * (r >> 2);
          if (kvb + kvl > q_global) S0[r] = -3e38f;
          if (kvb + 32 + kvl > q_global) S1[r] = -3e38f;
        }
      }
      float pm = -3e38f;
#pragma unroll
      for (int r = 0; r < 16; ++r) pm = fmaxf(pm, fmaxf(S0[r], S1[r]));
      pm = fmaxf(pm, __shfl_xor(pm, 32));
      if (!__all(pm - mrun <= 8.0f)) {
        const float mnew = fmaxf(mrun, pm);
        const float alpha = exp2f(mrun - mnew);
        lrun *= alpha;
#pragma unroll
        for (int r = 0; r < 16; ++r) {
          float ar = __shfl(alpha, 4 * h + (r & 3) + 8 * (r >> 2));
          accO[0][r] *= ar;
          accO[1][r] *= ar;
        }
        mrun = mnew;
      }
      float ladd = 0.f;
#pragma unroll
      for (int r = 0; r < 16; ++r) {
        float p0 = exp2f(S0[r] - mrun);
        float p1 = exp2f(S1[r] - mrun);
        S0[r] = p0; S1[r] = p1;
        ladd += p0 + p1;
      }
      ladd += __shfl_xor(ladd, 32);
      lrun += ladd;
      s16x8 pa[4];
      BUILD_PA(pa[0], S0, 0);
      BUILD_PA(pa[1], S0, 8);
      BUILD_PA(pa[2], S1, 0);
      BUILD_PA(pa[3], S1, 8);
      __builtin_amdgcn_s_setprio(1);
#pragma unroll
      for (int s = 0; s < 4; ++s) {
#pragma unroll
        for (int dt = 0; dt < 2; ++dt) {
          s16x8 vf = *(const s16x8*)(Vt[cb2] + (dt * 32 + ql) * 72 + 8 * h + 16 * s);
          accO[dt] = __builtin_amdgcn_mfma_f32_32x32x16_bf16(pa[s], vf, accO[dt], 0, 0, 0);
        }
      }
      __builtin_amdgcn_s_setprio(0);
    }
    asm volatile("s_waitcnt vmcnt(0)" ::: "memory");
    if (it < ntk) {
#pragma unroll
      for (int j = 0; j < 8; ++j) {
        unsigned pk = (unsigned)(unsigned short)va[j] | ((unsigned)(unsigned short)vb2[j] << 16);
        *(unsigned*)((char*)Vt[buf] + (size_t)((dbase + j) * 72 + kv0) * 2) = pk;
      }
    }
    __syncthreads();
  }
  const float linv = 1.0f / lrun;
  const int bb = bh >> 4, hh = bh & 15;
#pragma unroll
  for (int r = 0; r < 16; ++r) {
    const int qrow = 4 * h + (r & 3) + 8 * (r >> 2);
    const float lr = __shfl(linv, qrow);
    const int sg = qt * 128 + w * 32 + qrow;
    const size_t base = ((size_t)(bb * 2048 + sg)) * 1024 + hh * 64 + ql;
    O[base] = f2b(accO[0][r] * lr);
    O[base + 32] = f2b(accO[1][r] * lr);
  }
}

// ---------------- launch ----------------
extern "C" void kernel_launch(void* const* d_in, const int* in_sizes, int n_in,
                              void* d_out, int out_size, void* d_ws, size_t ws_size,
                              hipStream_t stream) {
  const float* x  = (const float*)d_in[0];
  const float* Wq = (const float*)d_in[1];
  const float* Wk = (const float*)d_in[2];
  const float* Wv = (const float*)d_in[3];
  const float* Wo = (const float*)d_in[4];
  char* ws = (char*)d_ws;
  unsigned short* xb   = (unsigned short*)(ws);               // 16 MB  [8192][1024]
  unsigned short* wqkv = (unsigned short*)(ws + 16777216);    // 6 MB   [3072][1024]
  unsigned short* wo   = (unsigned short*)(ws + 23068672);    // 2 MB   [1024][1024]
  unsigned short* qb   = (unsigned short*)(ws + 25165824);    // 16 MB  [64][2048][64]
  unsigned short* kb   = (unsigned short*)(ws + 41943040);    // 16 MB
  unsigned short* vb   = (unsigned short*)(ws + 58720256);    // 16 MB
  unsigned short* ab   = (unsigned short*)(ws + 75497472);    // 16 MB  [8192][1024]
  float* cosT = (float*)(ws + 92274688);                      // 256 KB
  float* sinT = (float*)(ws + 92536832);                      // 256 KB

  cvt_f2b_kernel<<<4096, 256, 0, stream>>>(x, xb, 1048576);
  cvt_f2b_kernel<<<512, 256, 0, stream>>>(Wq, wqkv, 131072);
  cvt_f2b_kernel<<<512, 256, 0, stream>>>(Wk, wqkv + 1048576, 131072);
  cvt_f2b_kernel<<<512, 256, 0, stream>>>(Wv, wqkv + 2097152, 131072);
  cvt_f2b_kernel<<<512, 256, 0, stream>>>(Wo, wo, 131072);
  rope_table_kernel<<<256, 256, 0, stream>>>(cosT, sinT);
  gemm256_kernel<1><<<768, 512, 0, stream>>>(xb, wqkv, nullptr, qb, kb, vb, 8192, 3072, 1024);
  // Q scale folds 1/sqrt(dk) AND log2(e): attention softmax runs in base-2
  rope_apply_kernel<<<4096, 256, 0, stream>>>(qb, cosT, sinT, 0.125f * 1.44269504f);
  rope_apply_kernel<<<4096, 256, 0, stream>>>(kb, cosT, sinT, 1.0f);
  attn_kernel<<<dim3(64, 16), 256, 0, stream>>>(qb, kb, vb, ab);
  gemm256_kernel<0><<<256, 512, 0, stream>>>(ab, wo, (float*)d_out, nullptr, nullptr, nullptr, 8192, 1024, 1024);
}